// Round 6
// baseline (33.639 us; speedup 1.0000x reference)
//
#include <hip/hip_runtime.h>

typedef __fp16 h2 __attribute__((ext_vector_type(2)));
typedef float  f4 __attribute__((ext_vector_type(4)));

#if __has_builtin(__builtin_amdgcn_fdot2)
#define FDOT2(a, b, c) __builtin_amdgcn_fdot2((a), (b), (c), false)
#else
#define FDOT2(a, b, c) ((c) + (float)(a)[0] * (float)(b)[0] + (float)(a)[1] * (float)(b)[1])
#endif

#define SPB 16
#define NT  320   // 20 threads per sample: (frame 0..9) x (half 0..1)

// fp16 rows of 24 elems (48 B, 16B-aligned), 10 rows + 8 pad = 248 fp16/sample
struct SMm {
    __fp16 x [SPB * 248];   // intra out + pos_inter (stage A -> B)
    __fp16 kk[SPB * 248];   // k rows fp16 (12 h2/row)
    __fp16 vv[SPB * 248];   // v rows fp16
    float  a [SPB * 104];   // normalized attn weights, 10/row + 4 pad
    h2     w [63 * 12];     // fp16 W^T rows (q,k,v), bias at pair 10
};
union USm { SMm m; float sout[SPB * 210]; };   // sout aliases x+kk (dead by PV)

__global__ __launch_bounds__(NT, 5)
void crazy_attn_kernel(const float* __restrict__ state,      // (B,100)
                       const float* __restrict__ pos_intra,  // (10,1)
                       const float* __restrict__ wq_i, const float* __restrict__ bq_i,
                       const float* __restrict__ wk_i, const float* __restrict__ bk_i,
                       const float* __restrict__ wv_i, const float* __restrict__ bv_i,
                       const float* __restrict__ pos_inter,  // (10,20)
                       const float* __restrict__ wq, const float* __restrict__ bq,
                       const float* __restrict__ wk, const float* __restrict__ bk,
                       const float* __restrict__ wv, const float* __restrict__ bv,
                       float* __restrict__ out, int B)
{
    __shared__ USm sm;

    const int tid  = threadIdx.x;
    const int samp = tid / 20;
    const int sub  = tid - samp * 20;
    const int f    = sub % 10;        // frame == inter row
    const int h    = sub / 10;        // head (stage A) / half (stages B,C)
    const int gs   = blockIdx.x * SPB + samp;
    const int gsc  = (gs < B) ? gs : (B - 1);

    // ---- stage 0: stage weights (fp16, transposed, bias appended) ----
    if (tid < 63) {
        const int mm = tid / 21, c = tid - mm * 21;
        const float* W  = (mm == 0) ? wq : (mm == 1) ? wk : wv;
        const float* Bb = (mm == 0) ? bq : (mm == 1) ? bk : bv;
        float t24[24];
        #pragma unroll
        for (int j = 0; j < 20; ++j) t24[j] = W[j * 21 + c];
        t24[20] = Bb[c]; t24[21] = 0.f; t24[22] = 0.f; t24[23] = 0.f;
        h2* dst = &sm.m.w[tid * 12];
        #pragma unroll
        for (int p = 0; p < 12; ++p)
            dst[p] = __builtin_amdgcn_cvt_pkrtz(t24[2 * p], t24[2 * p + 1]);
    }

    // ---- stage A: intra attention, one head per thread ----
    {
        const float* sp = state + (size_t)gsc * 100 + f * 10;
        float xv[10];
        #pragma unroll
        for (int t = 0; t < 10; ++t) xv[t] = sp[t] + pos_intra[t];
        float xmx = xv[0], xmn = xv[0];
        #pragma unroll
        for (int t = 1; t < 10; ++t) { xmx = fmaxf(xmx, xv[t]); xmn = fminf(xmn, xv[t]); }

        const float wqh = wq_i[h], bqh = bq_i[h];
        const float wkh = wk_i[h];
        const float wvh = wv_i[h], bvh = bv_i[h];
        float vh[10], cs[10];
        #pragma unroll
        for (int t = 0; t < 10; ++t) {
            vh[t] = fmaf(xv[t], wvh, bvh);
            cs[t] = fmaf(xv[t], wqh, bqh) * wkh;    // k-bias cancels in softmax
        }
        __fp16* xrow = &sm.m.x[samp * 248 + f * 24];
        const float* prow = pos_inter + f * 20;
        #pragma unroll
        for (int s = 0; s < 10; ++s) {
            const float c  = cs[s];
            const float mx = c * ((c >= 0.f) ? xmx : xmn);   // exact max_t(c*x_t)
            const float cL = c * 1.44269504f;
            const float mL = mx * 1.44269504f;
            float sum = 0.f, o = 0.f;
            #pragma unroll
            for (int t = 0; t < 10; ++t) {
                const float e = __builtin_amdgcn_exp2f(fmaf(cL, xv[t], -mL));
                sum += e; o = fmaf(e, vh[t], o);
            }
            const float res = o * __builtin_amdgcn_rcpf(sum);
            xrow[2 * s + h] = (__fp16)(res + prow[2 * s + h]);
        }
    }
    __syncthreads();   // barrier 1: weights + x staged

    // ---- stage B: projections (fp16 dot2); q stays in p=0 registers ----
    h2 xp[11];
    {
        const __fp16* xr = &sm.m.x[samp * 248 + f * 24];
        #pragma unroll
        for (int i = 0; i < 10; ++i) xp[i] = *(const h2*)&xr[2 * i];
        h2 one; one[0] = (__fp16)1.f; one[1] = (__fp16)0.f;
        xp[10] = one;
    }

    auto DOT = [&](int row) -> float {
        union { uint4 u4[3]; h2 hh[12]; } W;
        const uint4* wr = (const uint4*)&sm.m.w[row * 12];
        W.u4[0] = wr[0]; W.u4[1] = wr[1]; W.u4[2] = wr[2];
        float acc = 0.f;
        #pragma unroll
        for (int i = 0; i < 11; ++i) acc = FDOT2(xp[i], W.hh[i], acc);
        return acc;
    };

    h2 qp[11];
    __fp16* krow = &sm.m.kk[samp * 248 + f * 24];
    __fp16* vrow = &sm.m.vv[samp * 248 + f * 24];
    if (h == 0) {
        float q[21];
        #pragma unroll
        for (int c = 0; c < 21; ++c) q[c] = DOT(c);
        #pragma unroll
        for (int j = 0; j < 10; ++j) qp[j] = __builtin_amdgcn_cvt_pkrtz(q[2 * j], q[2 * j + 1]);
        qp[10] = __builtin_amdgcn_cvt_pkrtz(q[20], 0.f);
        float kr[10];
        #pragma unroll
        for (int c = 0; c < 10; ++c) kr[c] = DOT(21 + c);
        #pragma unroll
        for (int j = 0; j < 5; ++j)
            *(h2*)&krow[2 * j] = __builtin_amdgcn_cvt_pkrtz(kr[2 * j], kr[2 * j + 1]);
    } else {
        float kr[11];
        #pragma unroll
        for (int c = 0; c < 11; ++c) kr[c] = DOT(31 + c);     // k cols 10..20
        #pragma unroll
        for (int j = 0; j < 5; ++j)
            *(h2*)&krow[2 * (5 + j)] = __builtin_amdgcn_cvt_pkrtz(kr[2 * j], kr[2 * j + 1]);
        *(h2*)&krow[20] = __builtin_amdgcn_cvt_pkrtz(kr[10], 0.f);
        *(h2*)&krow[22] = __builtin_amdgcn_cvt_pkrtz(0.f, 0.f);
        float vr[21];
        #pragma unroll
        for (int c = 0; c < 21; ++c) vr[c] = DOT(42 + c);
        #pragma unroll
        for (int j = 0; j < 10; ++j)
            *(h2*)&vrow[2 * j] = __builtin_amdgcn_cvt_pkrtz(vr[2 * j], vr[2 * j + 1]);
        *(h2*)&vrow[20] = __builtin_amdgcn_cvt_pkrtz(vr[20], 0.f);
        *(h2*)&vrow[22] = __builtin_amdgcn_cvt_pkrtz(0.f, 0.f);
    }
    __syncthreads();   // barrier 2: k/v staged

    // ---- stage C1: scores + softmax (p=0 lanes; q in regs) ----
    if (h == 0) {
        float sc[10], m = -1e30f;
        #pragma unroll
        for (int t = 0; t < 10; ++t) {
            union { uint4 u4[3]; h2 hh[12]; } K;
            const uint4* kr_ = (const uint4*)&sm.m.kk[samp * 248 + t * 24];
            K.u4[0] = kr_[0]; K.u4[1] = kr_[1]; K.u4[2] = kr_[2];
            float d = 0.f;
            #pragma unroll
            for (int i = 0; i < 11; ++i) d = FDOT2(qp[i], K.hh[i], d);
            d *= 0.21821789023599239f;   // 1/sqrt(21)
            sc[t] = d; m = fmaxf(m, d);
        }
        float sum = 0.f;
        #pragma unroll
        for (int t = 0; t < 10; ++t) {
            sc[t] = __builtin_amdgcn_exp2f((sc[t] - m) * 1.44269504f);
            sum += sc[t];
        }
        const float inv = __builtin_amdgcn_rcpf(sum);
        float* ar = &sm.m.a[samp * 104 + f * 10];
        #pragma unroll
        for (int t = 0; t < 10; ++t) ar[t] = sc[t] * inv;
    }
    __syncthreads();   // barrier 3: attn weights staged

    // ---- stage C2: PV, split by output-column half; write to staged sout --
    {
        const float* ar = &sm.m.a[samp * 104 + f * 10];
        float av[10];
        #pragma unroll
        for (int t = 0; t < 10; ++t) av[t] = ar[t];

        float acc[11];
        #pragma unroll
        for (int c = 0; c < 11; ++c) acc[c] = 0.f;

        if (h == 0) {          // cols 0..10 (pairs 0..5 -> read u4[0..1])
            #pragma unroll
            for (int t = 0; t < 10; ++t) {
                union { uint4 u4[2]; h2 hh[8]; } V;
                const uint4* vr_ = (const uint4*)&sm.m.vv[samp * 248 + t * 24];
                V.u4[0] = vr_[0]; V.u4[1] = vr_[1];
                #pragma unroll
                for (int c = 0; c < 11; ++c)
                    acc[c] = fmaf(av[t], (float)V.hh[c >> 1][c & 1], acc[c]);
            }
            float* dst = &sm.sout[samp * 210 + f * 21];
            // wait for all x/kk readers before overwriting via alias:
            // (x last read in stage B, kk in C1 -> both before barrier 3)  OK
            #pragma unroll
            for (int c = 0; c < 11; ++c) dst[c] = acc[c];
        } else {               // cols 11..20 (pairs 5..10 -> read u4[1..2])
            #pragma unroll
            for (int t = 0; t < 10; ++t) {
                union { uint4 u4[2]; h2 hh[8]; } V;
                const uint4* vr_ = (const uint4*)&sm.m.vv[samp * 248 + t * 24];
                V.u4[0] = vr_[1]; V.u4[1] = vr_[2];   // pairs 4..11
                #pragma unroll
                for (int c = 0; c < 10; ++c) {
                    const int col = 11 + c;            // pair col>>1 - 4 in hh
                    acc[c] = fmaf(av[t], (float)V.hh[(col >> 1) - 4][col & 1], acc[c]);
                }
            }
            float* dst = &sm.sout[samp * 210 + f * 21 + 11];
            #pragma unroll
            for (int c = 0; c < 10; ++c) dst[c] = acc[c];
        }
    }
    __syncthreads();   // barrier 4: sout staged

    // ---- epilogue: coalesced block copy ----
    {
        const int samp0 = blockIdx.x * SPB;
        const int nrem  = B - samp0;
        const int nval  = ((nrem < SPB) ? nrem : SPB) * 210;
        float* gdst = out + (size_t)samp0 * 210;
        if (nval == SPB * 210) {
            #pragma unroll
            for (int i = tid; i < SPB * 210 / 4; i += NT)
                ((f4*)gdst)[i] = ((const f4*)sm.sout)[i];
        } else {
            for (int i = tid; i < nval; i += NT) gdst[i] = sm.sout[i];
        }
    }
}

extern "C" void kernel_launch(void* const* d_in, const int* in_sizes, int n_in,
                              void* d_out, int out_size, void* d_ws, size_t ws_size,
                              hipStream_t stream) {
    const float* state     = (const float*)d_in[0];
    const float* pos_intra = (const float*)d_in[1];
    const float* wq_i      = (const float*)d_in[2];
    const float* bq_i      = (const float*)d_in[3];
    const float* wk_i      = (const float*)d_in[4];
    const float* bk_i      = (const float*)d_in[5];
    const float* wv_i      = (const float*)d_in[6];
    const float* bv_i      = (const float*)d_in[7];
    const float* pos_inter = (const float*)d_in[8];
    const float* wq        = (const float*)d_in[9];
    const float* bq        = (const float*)d_in[10];
    const float* wk        = (const float*)d_in[11];
    const float* bk        = (const float*)d_in[12];
    const float* wv        = (const float*)d_in[13];
    const float* bv        = (const float*)d_in[14];
    float* outp = (float*)d_out;

    const int B = in_sizes[0] / 100;
    const int grid = (B + SPB - 1) / SPB;
    hipLaunchKernelGGL(crazy_attn_kernel, dim3(grid), dim3(NT), 0, stream,
                       state, pos_intra, wq_i, bq_i, wk_i, bk_i, wv_i, bv_i,
                       pos_inter, wq, bq, wk, bk, wv, bv, outp, B);
}

// Round 7
// 30.020 us; speedup vs baseline: 1.1205x; 1.1205x over previous
//
#include <hip/hip_runtime.h>

typedef __fp16 h2 __attribute__((ext_vector_type(2)));
typedef float  f4 __attribute__((ext_vector_type(4)));

#if __has_builtin(__builtin_amdgcn_fdot2)
#define FDOT2(a, b, c) __builtin_amdgcn_fdot2((a), (b), (c), false)
#else
#define FDOT2(a, b, c) ((c) + (float)(a)[0] * (float)(b)[0] + (float)(a)[1] * (float)(b)[1])
#endif

#define SPB 8
#define NT  256   // 32 threads per sample

struct SMm {
    __fp16 x [SPB * 248];   // 3968 B: rows of 24 fp16 (20 data, [20]=1 bias, pads)
    __fp16 kk[SPB * 248];   // 3968 B: k rows fp16 (21 + pads)
    __fp16 vv[SPB * 160];   // 2560 B: rows of 16 fp16 = v cols 0..11
    __fp16 vs[SPB * 160];   // 2560 B: rows of 16 fp16 = v cols 11..21 (shifted copy)
    float  a [SPB * 120];   // 3840 B: attn rows of 12 f32 (10 data)
    h2     w [63 * 16];     // 4032 B: fp16 W^T rows (32B-aligned), bias at pair 10
};
union USm { SMm m; float sout[SPB * 210]; };  // sout (6720 B) aliases x+kk (7936 B)

__global__ __launch_bounds__(NT, 7)
void crazy_attn_kernel(const float* __restrict__ state,      // (B,100)
                       const float* __restrict__ pos_intra,  // (10,1)
                       const float* __restrict__ wq_i, const float* __restrict__ bq_i,
                       const float* __restrict__ wk_i, const float* __restrict__ bk_i,
                       const float* __restrict__ wv_i, const float* __restrict__ bv_i,
                       const float* __restrict__ pos_inter,  // (10,20)
                       const float* __restrict__ wq, const float* __restrict__ bq,
                       const float* __restrict__ wk, const float* __restrict__ bk,
                       const float* __restrict__ wv, const float* __restrict__ bv,
                       float* __restrict__ out, int B)
{
    __shared__ USm sm;

    const int tid  = threadIdx.x;
    const int samp = tid >> 5;         // 0..7
    const int u    = tid & 31;         // role within sample
    const int gs   = blockIdx.x * SPB + samp;
    const int gsc  = (gs < B) ? gs : (B - 1);

    // ---- stage 0: weights -> LDS (fp16, transposed, bias appended, 32B rows)
    if (tid < 63) {
        const int mm = tid / 21, c = tid - mm * 21;
        const float* W  = (mm == 0) ? wq : (mm == 1) ? wk : wv;
        const float* Bb = (mm == 0) ? bq : (mm == 1) ? bk : bv;
        h2* dst = &sm.m.w[tid * 16];
        #pragma unroll
        for (int p = 0; p < 10; ++p)
            dst[p] = __builtin_amdgcn_cvt_pkrtz(W[(2 * p) * 21 + c], W[(2 * p + 1) * 21 + c]);
        dst[10] = __builtin_amdgcn_cvt_pkrtz(Bb[c], 0.f);
        const h2 z = __builtin_amdgcn_cvt_pkrtz(0.f, 0.f);
        dst[11] = z; dst[12] = z; dst[13] = z; dst[14] = z; dst[15] = z;
    }

    // ---- stage A: intra attention, thread = (frame, head), masked u<20 ----
    if (u < 20) {
        const int f = u % 10, h = u / 10;
        const float* sp = state + (size_t)gsc * 100 + f * 10;
        float xv[10];
        #pragma unroll
        for (int t = 0; t < 10; ++t) xv[t] = sp[t] + pos_intra[t];
        float xmx = xv[0], xmn = xv[0];
        #pragma unroll
        for (int t = 1; t < 10; ++t) { xmx = fmaxf(xmx, xv[t]); xmn = fminf(xmn, xv[t]); }

        const float wqh = wq_i[h], bqh = bq_i[h];
        const float wkh = wk_i[h];
        const float wvh = wv_i[h], bvh = bv_i[h];
        float vh[10], cs[10];
        #pragma unroll
        for (int t = 0; t < 10; ++t) {
            vh[t] = fmaf(xv[t], wvh, bvh);
            cs[t] = fmaf(xv[t], wqh, bqh) * wkh;    // k-bias cancels in softmax
        }
        __fp16* xrow = &sm.m.x[samp * 248 + f * 24];
        const float* prow = pos_inter + f * 20;
        #pragma unroll
        for (int s = 0; s < 10; ++s) {
            const float c  = cs[s];
            const float mx = c * ((c >= 0.f) ? xmx : xmn);   // exact max_t(c*x_t)
            const float cL = c * 1.44269504f;
            const float mL = mx * 1.44269504f;
            float sum = 0.f, o = 0.f;
            #pragma unroll
            for (int t = 0; t < 10; ++t) {
                const float e = __builtin_amdgcn_exp2f(fmaf(cL, xv[t], -mL));
                sum += e; o = fmaf(e, vh[t], o);
            }
            const float res = o * __builtin_amdgcn_rcpf(sum);
            xrow[2 * s + h] = (__fp16)(res + prow[2 * s + h]);
        }
        if (h == 0) { xrow[20] = (__fp16)1.f; xrow[21] = (__fp16)0.f; }
        else        { xrow[22] = (__fp16)0.f; xrow[23] = (__fp16)0.f; }
    }
    __syncthreads();   // B1: weights + x staged

    // ---- stage B: projections, uniform 21-dot loop; which selects W base ---
    h2 qp[11];
    const int r = u % 10;
    if (u < 30) {
        const int which = u / 10;          // 0=q 1=k 2=v (data-only difference)
        union { uint4 u4[3]; h2 hh[12]; } X;
        const uint4* xr = (const uint4*)&sm.m.x[samp * 248 + r * 24];
        X.u4[0] = xr[0]; X.u4[1] = xr[1]; X.u4[2] = xr[2];

        float o[21];
        const int wbase = which * 21;
        #pragma unroll
        for (int c = 0; c < 21; ++c) {
            union { uint4 u4[3]; h2 hh[12]; } W;
            const uint4* wr = (const uint4*)&sm.m.w[(wbase + c) * 16];
            W.u4[0] = wr[0]; W.u4[1] = wr[1]; W.u4[2] = wr[2];
            float acc = 0.f;
            #pragma unroll
            for (int i = 0; i < 11; ++i) acc = FDOT2(X.hh[i], W.hh[i], acc);
            o[c] = acc;
        }

        if (which == 0) {          // q stays in registers (fp16 pairs)
            #pragma unroll
            for (int j = 0; j < 10; ++j)
                qp[j] = __builtin_amdgcn_cvt_pkrtz(o[2 * j], o[2 * j + 1]);
            qp[10] = __builtin_amdgcn_cvt_pkrtz(o[20], 0.f);
        } else if (which == 1) {   // k row -> LDS fp16
            union { uint4 u4[3]; h2 hh[12]; } K;
            #pragma unroll
            for (int j = 0; j < 10; ++j)
                K.hh[j] = __builtin_amdgcn_cvt_pkrtz(o[2 * j], o[2 * j + 1]);
            K.hh[10] = __builtin_amdgcn_cvt_pkrtz(o[20], 0.f);
            K.hh[11] = __builtin_amdgcn_cvt_pkrtz(0.f, 0.f);
            uint4* kd = (uint4*)&sm.m.kk[samp * 248 + r * 24];
            kd[0] = K.u4[0]; kd[1] = K.u4[1]; kd[2] = K.u4[2];
        } else {                   // v row -> LDS fp16, plain + shifted copy
            const h2 z = __builtin_amdgcn_cvt_pkrtz(0.f, 0.f);
            union { uint4 u4[2]; h2 hh[8]; } V0, V1;
            #pragma unroll
            for (int j = 0; j < 6; ++j)    // cols 0..11
                V0.hh[j] = __builtin_amdgcn_cvt_pkrtz(o[2 * j], o[2 * j + 1]);
            V0.hh[6] = z; V0.hh[7] = z;
            #pragma unroll
            for (int j = 0; j < 4; ++j)    // cols 11..18
                V1.hh[j] = __builtin_amdgcn_cvt_pkrtz(o[11 + 2 * j], o[12 + 2 * j]);
            V1.hh[4] = __builtin_amdgcn_cvt_pkrtz(o[19], o[20]);
            V1.hh[5] = z; V1.hh[6] = z; V1.hh[7] = z;
            uint4* vd = (uint4*)&sm.m.vv[samp * 160 + r * 16];
            vd[0] = V0.u4[0]; vd[1] = V0.u4[1];
            uint4* sd = (uint4*)&sm.m.vs[samp * 160 + r * 16];
            sd[0] = V1.u4[0]; sd[1] = V1.u4[1];
        }
    }
    __syncthreads();   // B2: k/v staged

    // ---- stage C1: scores + softmax (u<10; q in regs) ----
    if (u < 10) {
        float sc[10], m = -1e30f;
        #pragma unroll
        for (int t = 0; t < 10; ++t) {
            union { uint4 u4[3]; h2 hh[12]; } K;
            const uint4* kr_ = (const uint4*)&sm.m.kk[samp * 248 + t * 24];
            K.u4[0] = kr_[0]; K.u4[1] = kr_[1]; K.u4[2] = kr_[2];
            float d = 0.f;
            #pragma unroll
            for (int i = 0; i < 11; ++i) d = FDOT2(qp[i], K.hh[i], d);
            d *= 0.21821789023599239f;   // 1/sqrt(21)
            sc[t] = d; m = fmaxf(m, d);
        }
        float sum = 0.f;
        #pragma unroll
        for (int t = 0; t < 10; ++t) {
            sc[t] = __builtin_amdgcn_exp2f((sc[t] - m) * 1.44269504f);
            sum += sc[t];
        }
        const float inv = __builtin_amdgcn_rcpf(sum);
        float* ar = &sm.m.a[samp * 120 + u * 12];
        #pragma unroll
        for (int t = 0; t < 10; ++t) ar[t] = sc[t] * inv;
    }
    __syncthreads();   // B3: attn weights staged (kk/x now dead -> sout alias ok)

    // ---- stage C2: PV, thread = (row, half), uniform loop via shifted v ----
    if (u < 20) {
        const int rr = u % 10, hf = u / 10;
        const f4* ar4 = (const f4*)&sm.m.a[samp * 120 + rr * 12];
        const f4 a0 = ar4[0], a1 = ar4[1], a2 = ar4[2];
        float av[10] = { a0[0], a0[1], a0[2], a0[3],
                         a1[0], a1[1], a1[2], a1[3],
                         a2[0], a2[1] };
        const __fp16* vbase = hf ? sm.m.vs : sm.m.vv;   // uniform code, ptr select
        const uint4* vb = (const uint4*)&vbase[samp * 160];
        float acc[11];
        #pragma unroll
        for (int j = 0; j < 11; ++j) acc[j] = 0.f;
        #pragma unroll
        for (int t = 0; t < 10; ++t) {
            union { uint4 u4[2]; h2 hh[8]; } V;
            V.u4[0] = vb[t * 2]; V.u4[1] = vb[t * 2 + 1];
            #pragma unroll
            for (int j = 0; j < 11; ++j)
                acc[j] = fmaf(av[t], (float)V.hh[j >> 1][j & 1], acc[j]);
        }
        float* dst = &sm.sout[samp * 210 + rr * 21 + hf * 11];
        #pragma unroll
        for (int j = 0; j < 10; ++j) dst[j] = acc[j];
        if (!hf) dst[10] = acc[10];
    }
    __syncthreads();   // B4: sout staged

    // ---- epilogue: coalesced block copy ----
    {
        const int samp0 = blockIdx.x * SPB;
        const int nrem  = B - samp0;
        const int nval  = ((nrem < SPB) ? nrem : SPB) * 210;
        float* gdst = out + (size_t)samp0 * 210;
        if (nval == SPB * 210) {
            #pragma unroll
            for (int i = tid; i < SPB * 210 / 4; i += NT)
                ((f4*)gdst)[i] = ((const f4*)sm.sout)[i];
        } else {
            for (int i = tid; i < nval; i += NT) gdst[i] = sm.sout[i];
        }
    }
}

extern "C" void kernel_launch(void* const* d_in, const int* in_sizes, int n_in,
                              void* d_out, int out_size, void* d_ws, size_t ws_size,
                              hipStream_t stream) {
    const float* state     = (const float*)d_in[0];
    const float* pos_intra = (const float*)d_in[1];
    const float* wq_i      = (const float*)d_in[2];
    const float* bq_i      = (const float*)d_in[3];
    const float* wk_i      = (const float*)d_in[4];
    const float* bk_i      = (const float*)d_in[5];
    const float* wv_i      = (const float*)d_in[6];
    const float* bv_i      = (const float*)d_in[7];
    const float* pos_inter = (const float*)d_in[8];
    const float* wq        = (const float*)d_in[9];
    const float* bq        = (const float*)d_in[10];
    const float* wk        = (const float*)d_in[11];
    const float* bk        = (const float*)d_in[12];
    const float* wv        = (const float*)d_in[13];
    const float* bv        = (const float*)d_in[14];
    float* outp = (float*)d_out;

    const int B = in_sizes[0] / 100;
    const int grid = (B + SPB - 1) / SPB;
    hipLaunchKernelGGL(crazy_attn_kernel, dim3(grid), dim3(NT), 0, stream,
                       state, pos_intra, wq_i, bq_i, wk_i, bk_i, wv_i, bv_i,
                       pos_inter, wq, bq, wk, bk, wv, bv, outp, B);
}

// Round 8
// 27.060 us; speedup vs baseline: 1.2431x; 1.1094x over previous
//
#include <hip/hip_runtime.h>

typedef __fp16 h2 __attribute__((ext_vector_type(2)));
typedef __fp16 h4 __attribute__((ext_vector_type(4)));
typedef __fp16 h8 __attribute__((ext_vector_type(8)));
typedef float  f4 __attribute__((ext_vector_type(4)));

#if __has_builtin(__builtin_amdgcn_fdot2)
#define FDOT2(a, b, c) __builtin_amdgcn_fdot2((a), (b), (c), false)
#else
#define FDOT2(a, b, c) ((c) + (float)(a)[0] * (float)(b)[0] + (float)(a)[1] * (float)(b)[1])
#endif

#define SPB 32
#define NT  320

// LDS:
//  X  [320][32] fp16 : x rows, K-padded: [20 data][1.0 bias][11 zeros]
//  WT [80][32]  fp16 : W^T rows; c: 0..20 q, 24..44 k, 48..68 v, rest zero
//  QKV[320][80] fp16 : per x-row [q 0..23][k 24..47][v 48..71][pad 72..79]
struct SMa {
    __fp16 X [320 * 32];    // 20480 B
    __fp16 WT[80 * 32];     //  5120 B
    __fp16 pad_[640];       //  1280 B
};
union UHead { SMa a; float sout[SPB * 210]; };   // 26880 B exact alias

__global__ __launch_bounds__(NT, 2)
void crazy_attn_kernel(const float* __restrict__ state,      // (B,100)
                       const float* __restrict__ pos_intra,  // (10,1)
                       const float* __restrict__ wq_i, const float* __restrict__ bq_i,
                       const float* __restrict__ wk_i, const float* __restrict__ bk_i,
                       const float* __restrict__ wv_i, const float* __restrict__ bv_i,
                       const float* __restrict__ pos_inter,  // (10,20)
                       const float* __restrict__ wq, const float* __restrict__ bq,
                       const float* __restrict__ wk, const float* __restrict__ bk,
                       const float* __restrict__ wv, const float* __restrict__ bv,
                       float* __restrict__ out, int B)
{
    __shared__ UHead uh;
    __shared__ __fp16 QKV[320 * 80];   // 51200 B

    const int tid  = threadIdx.x;
    const int samp = tid / 10;         // 0..31
    const int r    = tid - samp * 10;  // frame == inter row
    const int gs   = blockIdx.x * SPB + samp;
    const int gsc  = (gs < B) ? gs : (B - 1);

    // ---- stage 0: W^T -> LDS (fp16, K-padded rows, bias at k=20) ----
    if (tid < 80) {
        const int c  = tid;
        const int g  = c / 24;          // 0=q 1=k 2=v 3=pad
        const int cc = c - g * 24;      // 0..23
        const bool valid = (g < 3) && (cc < 21);
        const float* W  = (g == 1) ? wk : (g == 2) ? wv : wq;
        const float* Bb = (g == 1) ? bk : (g == 2) ? bv : bq;
        union { uint4 u4[4]; h2 hh[16]; } T;
        #pragma unroll
        for (int p = 0; p < 16; ++p) {
            const int j0 = 2 * p, j1 = 2 * p + 1;
            float lo = 0.f, hi = 0.f;
            if (valid) {
                lo = (j0 < 20) ? W[j0 * 21 + cc] : ((j0 == 20) ? Bb[cc] : 0.f);
                hi = (j1 < 20) ? W[j1 * 21 + cc] : ((j1 == 20) ? Bb[cc] : 0.f);
            }
            T.hh[p] = __builtin_amdgcn_cvt_pkrtz(lo, hi);
        }
        uint4* wd = (uint4*)&uh.a.WT[c * 32];
        wd[0] = T.u4[0]; wd[1] = T.u4[1]; wd[2] = T.u4[2]; wd[3] = T.u4[3];
    }

    // ---- stage A: intra attention (registers; rank-1 score trick) -> X row
    {
        const float* sp = state + (size_t)gsc * 100 + r * 10;
        float xv[10];
        #pragma unroll
        for (int t = 0; t < 10; ++t) xv[t] = sp[t] + pos_intra[t];
        float xmx = xv[0], xmn = xv[0];
        #pragma unroll
        for (int t = 1; t < 10; ++t) { xmx = fmaxf(xmx, xv[t]); xmn = fminf(xmn, xv[t]); }

        float x[20];
        #pragma unroll
        for (int h = 0; h < 2; ++h) {
            const float wqh = wq_i[h], bqh = bq_i[h];
            const float wkh = wk_i[h];
            const float wvh = wv_i[h], bvh = bv_i[h];
            float vh[10], cs[10];
            #pragma unroll
            for (int t = 0; t < 10; ++t) {
                vh[t] = fmaf(xv[t], wvh, bvh);
                cs[t] = fmaf(xv[t], wqh, bqh) * wkh;   // k-bias cancels in softmax
            }
            #pragma unroll
            for (int s = 0; s < 10; ++s) {
                const float c  = cs[s];
                const float mx = c * ((c >= 0.f) ? xmx : xmn);  // exact max_t(c*x_t)
                const float cL = c * 1.44269504f;
                const float mL = mx * 1.44269504f;
                float sum = 0.f, o = 0.f;
                #pragma unroll
                for (int t = 0; t < 10; ++t) {
                    const float e = __builtin_amdgcn_exp2f(fmaf(cL, xv[t], -mL));
                    sum += e; o = fmaf(e, vh[t], o);
                }
                x[s * 2 + h] = o * __builtin_amdgcn_rcpf(sum);
            }
        }
        const float* prow = pos_inter + r * 20;
        union { uint4 u4[4]; h2 hh[16]; } XR;
        #pragma unroll
        for (int p = 0; p < 10; ++p)
            XR.hh[p] = __builtin_amdgcn_cvt_pkrtz(x[2 * p] + prow[2 * p],
                                                  x[2 * p + 1] + prow[2 * p + 1]);
        XR.hh[10] = __builtin_amdgcn_cvt_pkrtz(1.0f, 0.f);     // bias input at k=20
        const h2 z = __builtin_amdgcn_cvt_pkrtz(0.f, 0.f);
        XR.hh[11] = z; XR.hh[12] = z; XR.hh[13] = z; XR.hh[14] = z; XR.hh[15] = z;
        uint4* xd = (uint4*)&uh.a.X[(samp * 10 + r) * 32];
        xd[0] = XR.u4[0]; xd[1] = XR.u4[1]; xd[2] = XR.u4[2]; xd[3] = XR.u4[3];
    }
    __syncthreads();   // B1: X + WT staged

    // ---- stage B: projections as MFMA GEMM  D(80x320) = WT(80x32) . X^T(32x320)
    {
        const int l  = tid & 63;
        const int w  = tid >> 6;        // wave 0..4
        const int lr = l & 15, lh = l >> 4;
        h8 afrag[5];
        #pragma unroll
        for (int mt = 0; mt < 5; ++mt)
            afrag[mt] = *(const h8*)&uh.a.WT[(mt * 16 + lr) * 32 + lh * 8];
        #pragma unroll
        for (int i = 0; i < 4; ++i) {
            const int nt   = 4 * w + i;
            const int xrow = nt * 16 + lr;
            const h8 bfrag = *(const h8*)&uh.a.X[xrow * 32 + lh * 8];
            #pragma unroll
            for (int mt = 0; mt < 5; ++mt) {
                f4 acc = {0.f, 0.f, 0.f, 0.f};
                acc = __builtin_amdgcn_mfma_f32_16x16x32_f16(afrag[mt], bfrag, acc, 0, 0, 0);
                const int c0 = mt * 16 + lh * 4;   // 4 consecutive c per lane
                union { h2 p2[2]; h4 p4; } P;
                P.p2[0] = __builtin_amdgcn_cvt_pkrtz(acc[0], acc[1]);
                P.p2[1] = __builtin_amdgcn_cvt_pkrtz(acc[2], acc[3]);
                *(h4*)&QKV[xrow * 80 + c0] = P.p4;
            }
        }
    }
    __syncthreads();   // B2: QKV staged; X/WT dead -> sout alias safe

    // ---- stage C: inter attention, thread = (sample, row) ----
    {
        const __fp16* samprows = &QKV[samp * 10 * 80];
        union { uint4 u4[3]; h2 hh[12]; } Q;
        {
            const uint4* qsrc = (const uint4*)&samprows[r * 80];   // cols 0..23
            Q.u4[0] = qsrc[0]; Q.u4[1] = qsrc[1]; Q.u4[2] = qsrc[2];
        }
        float sc[10], m = -1e30f;
        #pragma unroll
        for (int t = 0; t < 10; ++t) {
            union { uint4 u4[3]; h2 hh[12]; } K;
            const uint4* ks = (const uint4*)&samprows[t * 80 + 24]; // cols 24..47
            K.u4[0] = ks[0]; K.u4[1] = ks[1]; K.u4[2] = ks[2];
            float d = 0.f;
            #pragma unroll
            for (int p = 0; p < 11; ++p) d = FDOT2(Q.hh[p], K.hh[p], d);
            d *= 0.21821789023599239f;   // 1/sqrt(21); pad terms are exact zeros
            sc[t] = d; m = fmaxf(m, d);
        }
        float sum = 0.f;
        #pragma unroll
        for (int t = 0; t < 10; ++t) {
            sc[t] = __builtin_amdgcn_exp2f((sc[t] - m) * 1.44269504f);
            sum += sc[t];
        }
        const float inv = __builtin_amdgcn_rcpf(sum);

        float acc[21];
        #pragma unroll
        for (int c = 0; c < 21; ++c) acc[c] = 0.f;
        #pragma unroll
        for (int t = 0; t < 10; ++t) {
            union { uint4 u4[3]; h2 hh[12]; } V;
            const uint4* vs = (const uint4*)&samprows[t * 80 + 48]; // cols 48..71
            V.u4[0] = vs[0]; V.u4[1] = vs[1]; V.u4[2] = vs[2];
            const float a = sc[t] * inv;
            #pragma unroll
            for (int c = 0; c < 21; ++c)
                acc[c] = fmaf(a, (float)V.hh[c >> 1][c & 1], acc[c]);  // v_fma_mix
        }
        float* dst = &uh.sout[(samp * 10 + r) * 21];
        #pragma unroll
        for (int c = 0; c < 21; ++c) dst[c] = acc[c];
    }
    __syncthreads();   // B3: sout staged

    // ---- epilogue: coalesced block copy ----
    {
        const int samp0 = blockIdx.x * SPB;
        const int nrem  = B - samp0;
        const int nval  = ((nrem < SPB) ? nrem : SPB) * 210;
        float* gdst = out + (size_t)samp0 * 210;
        if (nval == SPB * 210) {
            #pragma unroll
            for (int i = tid; i < SPB * 210 / 4; i += NT)
                ((f4*)gdst)[i] = ((const f4*)uh.sout)[i];
        } else {
            for (int i = tid; i < nval; i += NT) gdst[i] = uh.sout[i];
        }
    }
}

extern "C" void kernel_launch(void* const* d_in, const int* in_sizes, int n_in,
                              void* d_out, int out_size, void* d_ws, size_t ws_size,
                              hipStream_t stream) {
    const float* state     = (const float*)d_in[0];
    const float* pos_intra = (const float*)d_in[1];
    const float* wq_i      = (const float*)d_in[2];
    const float* bq_i      = (const float*)d_in[3];
    const float* wk_i      = (const float*)d_in[4];
    const float* bk_i      = (const float*)d_in[5];
    const float* wv_i      = (const float*)d_in[6];
    const float* bv_i      = (const float*)d_in[7];
    const float* pos_inter = (const float*)d_in[8];
    const float* wq        = (const float*)d_in[9];
    const float* bq        = (const float*)d_in[10];
    const float* wk        = (const float*)d_in[11];
    const float* bk        = (const float*)d_in[12];
    const float* wv        = (const float*)d_in[13];
    const float* bv        = (const float*)d_in[14];
    float* outp = (float*)d_out;

    const int B = in_sizes[0] / 100;
    const int grid = (B + SPB - 1) / SPB;
    hipLaunchKernelGGL(crazy_attn_kernel, dim3(grid), dim3(NT), 0, stream,
                       state, pos_intra, wq_i, bq_i, wk_i, bk_i, wv_i, bv_i,
                       pos_inter, wq, bq, wk, bk, wv, bv, outp, B);
}

// Round 9
// 25.973 us; speedup vs baseline: 1.2951x; 1.0418x over previous
//
#include <hip/hip_runtime.h>

typedef __fp16 h2 __attribute__((ext_vector_type(2)));
typedef __fp16 h4 __attribute__((ext_vector_type(4)));
typedef __fp16 h8 __attribute__((ext_vector_type(8)));
typedef float  f4 __attribute__((ext_vector_type(4)));

#if __has_builtin(__builtin_amdgcn_fdot2)
#define FDOT2(a, b, c) __builtin_amdgcn_fdot2((a), (b), (c), false)
#else
#define FDOT2(a, b, c) ((c) + (float)(a)[0] * (float)(b)[0] + (float)(a)[1] * (float)(b)[1])
#endif

#define SPB 32
#define NT  640   // 20 threads per sample: (row 0..9) x (e 0..1), e = tid&1

// lane^1 exchange on the VALU pipe (quad_perm [1,0,3,2] = 0xB1), no LDS traffic
__device__ __forceinline__ float dpp_xor1(float x) {
    int i = __builtin_amdgcn_mov_dpp(__float_as_int(x), 0xB1, 0xF, 0xF, true);
    return __int_as_float(i);
}

// LDS:
//  X  [320][32] fp16 : x rows, K-padded: [20 data][1.0 bias][11 zeros]
//  WT [80][32]  fp16 : W^T rows; c: 0..20 q, 24..44 k, 48..68 v, rest zero
//  QKV[320][80] fp16 : per x-row [q 0..23][k 24..47][v 48..71][pad 72..79]
struct SMa {
    __fp16 X [320 * 32];    // 20480 B
    __fp16 WT[80 * 32];     //  5120 B
    __fp16 pad_[640];       //  1280 B
};
union UHead { SMa a; float sout[SPB * 210]; };   // 26880 B exact alias

__global__ __launch_bounds__(NT, 5)
void crazy_attn_kernel(const float* __restrict__ state,      // (B,100)
                       const float* __restrict__ pos_intra,  // (10,1)
                       const float* __restrict__ wq_i, const float* __restrict__ bq_i,
                       const float* __restrict__ wk_i, const float* __restrict__ bk_i,
                       const float* __restrict__ wv_i, const float* __restrict__ bv_i,
                       const float* __restrict__ pos_inter,  // (10,20)
                       const float* __restrict__ wq, const float* __restrict__ bq,
                       const float* __restrict__ wk, const float* __restrict__ bk,
                       const float* __restrict__ wv, const float* __restrict__ bv,
                       float* __restrict__ out, int B)
{
    __shared__ UHead uh;
    __shared__ __fp16 QKV[320 * 80];   // 51200 B

    const int tid  = threadIdx.x;
    const int e    = tid & 1;               // pair lane (xor-1 partner)
    const int rr   = (tid >> 1) % 10;       // frame == inter row
    const int samp = tid / 20;              // 0..31
    const int gs   = blockIdx.x * SPB + samp;
    const int gsc  = (gs < B) ? gs : (B - 1);

    // ---- stage 0: W^T -> LDS (fp16, K-padded rows, bias at k=20) ----
    if (tid < 80) {
        const int c  = tid;
        const int g  = c / 24;          // 0=q 1=k 2=v 3=pad
        const int cc = c - g * 24;      // 0..23
        const bool valid = (g < 3) && (cc < 21);
        const float* W  = (g == 1) ? wk : (g == 2) ? wv : wq;
        const float* Bb = (g == 1) ? bk : (g == 2) ? bv : bq;
        union { uint4 u4[4]; h2 hh[16]; } T;
        #pragma unroll
        for (int p = 0; p < 16; ++p) {
            const int j0 = 2 * p, j1 = 2 * p + 1;
            float lo = 0.f, hi = 0.f;
            if (valid) {
                lo = (j0 < 20) ? W[j0 * 21 + cc] : ((j0 == 20) ? Bb[cc] : 0.f);
                hi = (j1 < 20) ? W[j1 * 21 + cc] : ((j1 == 20) ? Bb[cc] : 0.f);
            }
            T.hh[p] = __builtin_amdgcn_cvt_pkrtz(lo, hi);
        }
        uint4* wd = (uint4*)&uh.a.WT[c * 32];
        wd[0] = T.u4[0]; wd[1] = T.u4[1]; wd[2] = T.u4[2]; wd[3] = T.u4[3];
    }

    // ---- stage A: intra attention; e splits query rows (s = 2*si + e) ----
    {
        const float* sp = state + (size_t)gsc * 100 + rr * 10;
        float xv[10];
        #pragma unroll
        for (int t = 0; t < 10; ++t) xv[t] = sp[t] + pos_intra[t];
        float xmx = xv[0], xmn = xv[0];
        #pragma unroll
        for (int t = 1; t < 10; ++t) { xmx = fmaxf(xmx, xv[t]); xmn = fminf(xmn, xv[t]); }

        float res[2][5];   // [h][si]
        #pragma unroll
        for (int h = 0; h < 2; ++h) {
            const float wqh = wq_i[h], bqh = bq_i[h];
            const float wkh = wk_i[h];
            const float wvh = wv_i[h], bvh = bv_i[h];
            float vh[10];
            #pragma unroll
            for (int t = 0; t < 10; ++t) vh[t] = fmaf(xv[t], wvh, bvh);
            #pragma unroll
            for (int si = 0; si < 5; ++si) {
                const float c0 = fmaf(xv[2 * si],     wqh, bqh) * wkh;
                const float c1 = fmaf(xv[2 * si + 1], wqh, bqh) * wkh;
                const float c  = e ? c1 : c0;                      // s = 2*si+e
                const float mx = c * ((c >= 0.f) ? xmx : xmn);     // exact max
                const float cL = c * 1.44269504f;
                const float mL = mx * 1.44269504f;
                float sum = 0.f, o = 0.f;
                #pragma unroll
                for (int t = 0; t < 10; ++t) {
                    const float ex = __builtin_amdgcn_exp2f(fmaf(cL, xv[t], -mL));
                    sum += ex; o = fmaf(ex, vh[t], o);
                }
                res[h][si] = o * __builtin_amdgcn_rcpf(sum);
            }
        }
        // write 5 feature-pairs (k = 2s, 2s+1), s = 2*si+e
        __fp16* xrow = &uh.a.X[(samp * 10 + rr) * 32];
        const float* prow = pos_inter + rr * 20;
        #pragma unroll
        for (int si = 0; si < 5; ++si) {
            const int s = 2 * si + e;
            *(h2*)&xrow[2 * s] = __builtin_amdgcn_cvt_pkrtz(res[0][si] + prow[2 * s],
                                                            res[1][si] + prow[2 * s + 1]);
        }
        // pads: e0 -> pairs k=20(bias),22,24 ; e1 -> 26,28,30
        const h2 z  = __builtin_amdgcn_cvt_pkrtz(0.f, 0.f);
        const h2 bz = __builtin_amdgcn_cvt_pkrtz(1.0f, 0.f);
        #pragma unroll
        for (int j = 0; j < 3; ++j) {
            const int k = 20 + 2 * (3 * e + j);
            *(h2*)&xrow[k] = (e == 0 && j == 0) ? bz : z;
        }
    }
    __syncthreads();   // B1: X + WT staged

    // ---- stage B: MFMA GEMM  D(80x320) = WT(80x32) . X^T(32x320), 10 waves
    {
        const int l  = tid & 63;
        const int w  = tid >> 6;        // wave 0..9
        const int lr = l & 15, lh = l >> 4;
        h8 afrag[5];
        #pragma unroll
        for (int mt = 0; mt < 5; ++mt)
            afrag[mt] = *(const h8*)&uh.a.WT[(mt * 16 + lr) * 32 + lh * 8];
        #pragma unroll
        for (int i = 0; i < 2; ++i) {
            const int nt   = 2 * w + i;
            const int xrow = nt * 16 + lr;
            const h8 bfrag = *(const h8*)&uh.a.X[xrow * 32 + lh * 8];
            #pragma unroll
            for (int mt = 0; mt < 5; ++mt) {
                f4 acc = {0.f, 0.f, 0.f, 0.f};
                acc = __builtin_amdgcn_mfma_f32_16x16x32_f16(afrag[mt], bfrag, acc, 0, 0, 0);
                const int c0 = mt * 16 + lh * 4;
                union { h2 p2[2]; h4 p4; } P;
                P.p2[0] = __builtin_amdgcn_cvt_pkrtz(acc[0], acc[1]);
                P.p2[1] = __builtin_amdgcn_cvt_pkrtz(acc[2], acc[3]);
                *(h4*)&QKV[xrow * 80 + c0] = P.p4;
            }
        }
    }
    __syncthreads();   // B2: QKV staged; X/WT dead -> sout alias safe

    // ---- stage C: inter attention; e splits K/V tiles (t = 2i+e) ----
    {
        const __fp16* samprows = &QKV[samp * 10 * 80];
        union { uint4 u4[3]; h2 hh[12]; } Q;
        {
            const uint4* qsrc = (const uint4*)&samprows[rr * 80];   // cols 0..23
            Q.u4[0] = qsrc[0]; Q.u4[1] = qsrc[1]; Q.u4[2] = qsrc[2];
        }
        float mysc[5];
        #pragma unroll
        for (int i = 0; i < 5; ++i) {
            const int t = 2 * i + e;
            union { uint4 u4[3]; h2 hh[12]; } K;
            const uint4* ks = (const uint4*)&samprows[t * 80 + 24]; // cols 24..47
            K.u4[0] = ks[0]; K.u4[1] = ks[1]; K.u4[2] = ks[2];
            float d = 0.f;
            #pragma unroll
            for (int p = 0; p < 11; ++p) d = FDOT2(Q.hh[p], K.hh[p], d);
            mysc[i] = d * 0.21821789023599239f;   // 1/sqrt(21)
        }
        // cross-e softmax: max and sum via DPP xor-1 (no LDS)
        float mymax = mysc[0];
        #pragma unroll
        for (int i = 1; i < 5; ++i) mymax = fmaxf(mymax, mysc[i]);
        const float m = fmaxf(mymax, dpp_xor1(mymax));
        float pe[5], psum = 0.f;
        #pragma unroll
        for (int i = 0; i < 5; ++i) {
            pe[i] = __builtin_amdgcn_exp2f((mysc[i] - m) * 1.44269504f);
            psum += pe[i];
        }
        const float sum = psum + dpp_xor1(psum);
        const float inv = __builtin_amdgcn_rcpf(sum);

        float acc[21];
        #pragma unroll
        for (int c = 0; c < 21; ++c) acc[c] = 0.f;
        #pragma unroll
        for (int i = 0; i < 5; ++i) {
            const int t = 2 * i + e;
            union { uint4 u4[3]; h2 hh[12]; } V;
            const uint4* vs = (const uint4*)&samprows[t * 80 + 48]; // cols 48..71
            V.u4[0] = vs[0]; V.u4[1] = vs[1]; V.u4[2] = vs[2];
            const float a = pe[i] * inv;
            #pragma unroll
            for (int c = 0; c < 21; ++c)
                acc[c] = fmaf(a, (float)V.hh[c >> 1][c & 1], acc[c]);  // v_fma_mix
        }
        // cross-e reduce via DPP; e0 lane writes the row
        #pragma unroll
        for (int c = 0; c < 21; ++c) acc[c] += dpp_xor1(acc[c]);
        if (e == 0) {
            float* dst = &uh.sout[(samp * 10 + rr) * 21];
            #pragma unroll
            for (int c = 0; c < 21; ++c) dst[c] = acc[c];
        }
    }
    __syncthreads();   // B3: sout staged

    // ---- epilogue: coalesced block copy ----
    {
        const int samp0 = blockIdx.x * SPB;
        const int nrem  = B - samp0;
        const int nval  = ((nrem < SPB) ? nrem : SPB) * 210;
        float* gdst = out + (size_t)samp0 * 210;
        if (nval == SPB * 210) {
            for (int i = tid; i < SPB * 210 / 4; i += NT)
                ((f4*)gdst)[i] = ((const f4*)uh.sout)[i];
        } else {
            for (int i = tid; i < nval; i += NT) gdst[i] = uh.sout[i];
        }
    }
}

extern "C" void kernel_launch(void* const* d_in, const int* in_sizes, int n_in,
                              void* d_out, int out_size, void* d_ws, size_t ws_size,
                              hipStream_t stream) {
    const float* state     = (const float*)d_in[0];
    const float* pos_intra = (const float*)d_in[1];
    const float* wq_i      = (const float*)d_in[2];
    const float* bq_i      = (const float*)d_in[3];
    const float* wk_i      = (const float*)d_in[4];
    const float* bk_i      = (const float*)d_in[5];
    const float* wv_i      = (const float*)d_in[6];
    const float* bv_i      = (const float*)d_in[7];
    const float* pos_inter = (const float*)d_in[8];
    const float* wq        = (const float*)d_in[9];
    const float* bq        = (const float*)d_in[10];
    const float* wk        = (const float*)d_in[11];
    const float* bk        = (const float*)d_in[12];
    const float* wv        = (const float*)d_in[13];
    const float* bv        = (const float*)d_in[14];
    float* outp = (float*)d_out;

    const int B = in_sizes[0] / 100;
    const int grid = (B + SPB - 1) / SPB;
    hipLaunchKernelGGL(crazy_attn_kernel, dim3(grid), dim3(NT), 0, stream,
                       state, pos_intra, wq_i, bq_i, wk_i, bk_i, wv_i, bv_i,
                       pos_inter, wq, bq, wk, bk, wv, bv, outp, B);
}

// Round 10
// 22.559 us; speedup vs baseline: 1.4911x; 1.1513x over previous
//
#include <hip/hip_runtime.h>

typedef __fp16 h2 __attribute__((ext_vector_type(2)));
typedef __fp16 h4 __attribute__((ext_vector_type(4)));
typedef __fp16 h8 __attribute__((ext_vector_type(8)));
typedef float  f4 __attribute__((ext_vector_type(4)));

#if __has_builtin(__builtin_amdgcn_fdot2)
#define FDOT2(a, b, c) __builtin_amdgcn_fdot2((a), (b), (c), false)
#else
#define FDOT2(a, b, c) ((c) + (float)(a)[0] * (float)(b)[0] + (float)(a)[1] * (float)(b)[1])
#endif

#define SPB 16
#define NT  320   // 20 threads/sample: (row 0..9) x (e 0..1); 5 waves/block

// lane^1 exchange on the VALU pipe (quad_perm [1,0,3,2]), no LDS traffic
__device__ __forceinline__ float dpp_xor1(float x) {
    int i = __builtin_amdgcn_mov_dpp(__float_as_int(x), 0xB1, 0xF, 0xF, true);
    return __int_as_float(i);
}

// LDS:
//  X  [160][32] fp16 : x rows, K-padded: [20 data][1.0 bias][11 zeros]
//  WT [80][32]  fp16 : W^T rows; c: 0..20 q, 24..44 k, 48..68 v, rest zero
//  QKV[160][72] fp16 : per x-row [q 0..23][k 24..47][v 48..71] (MFMA cols 72..79 dropped)
struct SMa {
    __fp16 X [160 * 32];    // 10240 B
    __fp16 WT[80 * 32];     //  5120 B
};
union UHead { SMa a; float sout[SPB * 210]; };   // 13440 B <= 15360 B alias

__global__ __launch_bounds__(NT, 5)
void crazy_attn_kernel(const float* __restrict__ state,      // (B,100)
                       const float* __restrict__ pos_intra,  // (10,1)
                       const float* __restrict__ wq_i, const float* __restrict__ bq_i,
                       const float* __restrict__ wk_i, const float* __restrict__ bk_i,
                       const float* __restrict__ wv_i, const float* __restrict__ bv_i,
                       const float* __restrict__ pos_inter,  // (10,20)
                       const float* __restrict__ wq, const float* __restrict__ bq,
                       const float* __restrict__ wk, const float* __restrict__ bk,
                       const float* __restrict__ wv, const float* __restrict__ bv,
                       float* __restrict__ out, int B)
{
    __shared__ UHead uh;
    __shared__ __fp16 QKV[160 * 72];   // 23040 B  (total LDS 38400 B -> 4 blocks/CU)

    const int tid  = threadIdx.x;
    const int e    = tid & 1;               // pair lane (xor-1 partner)
    const int rr   = (tid >> 1) % 10;       // frame == inter row
    const int samp = tid / 20;              // 0..15
    const int gs   = blockIdx.x * SPB + samp;
    const int gsc  = (gs < B) ? gs : (B - 1);

    // ---- stage 0: W^T -> LDS (fp16, K-padded rows, bias at k=20) ----
    if (tid < 80) {
        const int c  = tid;
        const int g  = c / 24;          // 0=q 1=k 2=v 3=pad
        const int cc = c - g * 24;      // 0..23
        const bool valid = (g < 3) && (cc < 21);
        const float* W  = (g == 1) ? wk : (g == 2) ? wv : wq;
        const float* Bb = (g == 1) ? bk : (g == 2) ? bv : bq;
        union { uint4 u4[4]; h2 hh[16]; } T;
        #pragma unroll
        for (int p = 0; p < 16; ++p) {
            const int j0 = 2 * p, j1 = 2 * p + 1;
            float lo = 0.f, hi = 0.f;
            if (valid) {
                lo = (j0 < 20) ? W[j0 * 21 + cc] : ((j0 == 20) ? Bb[cc] : 0.f);
                hi = (j1 < 20) ? W[j1 * 21 + cc] : ((j1 == 20) ? Bb[cc] : 0.f);
            }
            T.hh[p] = __builtin_amdgcn_cvt_pkrtz(lo, hi);
        }
        uint4* wd = (uint4*)&uh.a.WT[c * 32];
        wd[0] = T.u4[0]; wd[1] = T.u4[1]; wd[2] = T.u4[2]; wd[3] = T.u4[3];
    }

    // ---- stage A: intra attention; e splits query rows (s = 2*si + e) ----
    {
        const float* sp = state + (size_t)gsc * 100 + rr * 10;
        float xv[10];
        #pragma unroll
        for (int t = 0; t < 10; ++t) xv[t] = sp[t] + pos_intra[t];
        float xmx = xv[0], xmn = xv[0];
        #pragma unroll
        for (int t = 1; t < 10; ++t) { xmx = fmaxf(xmx, xv[t]); xmn = fminf(xmn, xv[t]); }

        float res[2][5];   // [h][si]
        #pragma unroll
        for (int h = 0; h < 2; ++h) {
            const float wqh = wq_i[h], bqh = bq_i[h];
            const float wkh = wk_i[h];
            const float wvh = wv_i[h], bvh = bv_i[h];
            float vh[10];
            #pragma unroll
            for (int t = 0; t < 10; ++t) vh[t] = fmaf(xv[t], wvh, bvh);
            #pragma unroll
            for (int si = 0; si < 5; ++si) {
                const float c0 = fmaf(xv[2 * si],     wqh, bqh) * wkh;
                const float c1 = fmaf(xv[2 * si + 1], wqh, bqh) * wkh;
                const float c  = e ? c1 : c0;                      // s = 2*si+e
                const float mx = c * ((c >= 0.f) ? xmx : xmn);     // exact max
                const float cL = c * 1.44269504f;
                const float mL = mx * 1.44269504f;
                float sum = 0.f, o = 0.f;
                #pragma unroll
                for (int t = 0; t < 10; ++t) {
                    const float ex = __builtin_amdgcn_exp2f(fmaf(cL, xv[t], -mL));
                    sum += ex; o = fmaf(ex, vh[t], o);
                }
                res[h][si] = o * __builtin_amdgcn_rcpf(sum);
            }
        }
        // write 5 feature-pairs (k = 2s, 2s+1), s = 2*si+e
        __fp16* xrow = &uh.a.X[(samp * 10 + rr) * 32];
        const float* prow = pos_inter + rr * 20;
        #pragma unroll
        for (int si = 0; si < 5; ++si) {
            const int s = 2 * si + e;
            *(h2*)&xrow[2 * s] = __builtin_amdgcn_cvt_pkrtz(res[0][si] + prow[2 * s],
                                                            res[1][si] + prow[2 * s + 1]);
        }
        // pads: e0 -> pairs k=20(bias),22,24 ; e1 -> 26,28,30
        const h2 z  = __builtin_amdgcn_cvt_pkrtz(0.f, 0.f);
        const h2 bz = __builtin_amdgcn_cvt_pkrtz(1.0f, 0.f);
        #pragma unroll
        for (int j = 0; j < 3; ++j) {
            const int k = 20 + 2 * (3 * e + j);
            *(h2*)&xrow[k] = (e == 0 && j == 0) ? bz : z;
        }
    }
    __syncthreads();   // B1: X + WT staged

    // ---- stage B: MFMA GEMM  D(80x160) = WT(80x32) . X^T(32x160), 5 waves
    {
        const int l  = tid & 63;
        const int w  = tid >> 6;        // wave 0..4
        const int lr = l & 15, lh = l >> 4;
        h8 afrag[5];
        #pragma unroll
        for (int mt = 0; mt < 5; ++mt)
            afrag[mt] = *(const h8*)&uh.a.WT[(mt * 16 + lr) * 32 + lh * 8];
        #pragma unroll
        for (int i = 0; i < 2; ++i) {
            const int nt   = 2 * w + i;
            const int xrow = nt * 16 + lr;
            const h8 bfrag = *(const h8*)&uh.a.X[xrow * 32 + lh * 8];
            #pragma unroll
            for (int mt = 0; mt < 5; ++mt) {
                f4 acc = {0.f, 0.f, 0.f, 0.f};
                acc = __builtin_amdgcn_mfma_f32_16x16x32_f16(afrag[mt], bfrag, acc, 0, 0, 0);
                const int c0 = mt * 16 + lh * 4;
                if (c0 < 72) {   // drop pad cols 72..79 (QKV rows are 72 wide)
                    union { h2 p2[2]; h4 p4; } P;
                    P.p2[0] = __builtin_amdgcn_cvt_pkrtz(acc[0], acc[1]);
                    P.p2[1] = __builtin_amdgcn_cvt_pkrtz(acc[2], acc[3]);
                    *(h4*)&QKV[xrow * 72 + c0] = P.p4;
                }
            }
        }
    }
    __syncthreads();   // B2: QKV staged; X/WT dead -> sout alias safe

    // ---- stage C: inter attention; e splits K/V tiles (t = 2i+e) ----
    {
        const __fp16* samprows = &QKV[samp * 10 * 72];
        union { uint4 u4[3]; h2 hh[12]; } Q;
        {
            const uint4* qsrc = (const uint4*)&samprows[rr * 72];   // cols 0..23
            Q.u4[0] = qsrc[0]; Q.u4[1] = qsrc[1]; Q.u4[2] = qsrc[2];
        }
        float mysc[5];
        #pragma unroll
        for (int i = 0; i < 5; ++i) {
            const int t = 2 * i + e;
            union { uint4 u4[3]; h2 hh[12]; } K;
            const uint4* ks = (const uint4*)&samprows[t * 72 + 24]; // cols 24..47
            K.u4[0] = ks[0]; K.u4[1] = ks[1]; K.u4[2] = ks[2];
            float d = 0.f;
            #pragma unroll
            for (int p = 0; p < 11; ++p) d = FDOT2(Q.hh[p], K.hh[p], d);
            mysc[i] = d * 0.21821789023599239f;   // 1/sqrt(21)
        }
        // cross-e softmax: max and sum via DPP xor-1 (no LDS)
        float mymax = mysc[0];
        #pragma unroll
        for (int i = 1; i < 5; ++i) mymax = fmaxf(mymax, mysc[i]);
        const float m = fmaxf(mymax, dpp_xor1(mymax));
        float pe[5], psum = 0.f;
        #pragma unroll
        for (int i = 0; i < 5; ++i) {
            pe[i] = __builtin_amdgcn_exp2f((mysc[i] - m) * 1.44269504f);
            psum += pe[i];
        }
        const float sum = psum + dpp_xor1(psum);
        const float inv = __builtin_amdgcn_rcpf(sum);

        float acc[21];
        #pragma unroll
        for (int c = 0; c < 21; ++c) acc[c] = 0.f;
        #pragma unroll
        for (int i = 0; i < 5; ++i) {
            const int t = 2 * i + e;
            union { uint4 u4[3]; h2 hh[12]; } V;
            const uint4* vs = (const uint4*)&samprows[t * 72 + 48]; // cols 48..71
            V.u4[0] = vs[0]; V.u4[1] = vs[1]; V.u4[2] = vs[2];
            const float a = pe[i] * inv;
            #pragma unroll
            for (int c = 0; c < 21; ++c)
                acc[c] = fmaf(a, (float)V.hh[c >> 1][c & 1], acc[c]);  // v_fma_mix
        }
        // cross-e reduce via DPP; e0 lane writes the row
        #pragma unroll
        for (int c = 0; c < 21; ++c) acc[c] += dpp_xor1(acc[c]);
        if (e == 0) {
            float* dst = &uh.sout[(samp * 10 + rr) * 21];
            #pragma unroll
            for (int c = 0; c < 21; ++c) dst[c] = acc[c];
        }
    }
    __syncthreads();   // B3: sout staged

    // ---- epilogue: coalesced block copy ----
    {
        const int samp0 = blockIdx.x * SPB;
        const int nrem  = B - samp0;
        const int nval  = ((nrem < SPB) ? nrem : SPB) * 210;
        float* gdst = out + (size_t)samp0 * 210;
        if (nval == SPB * 210) {
            for (int i = tid; i < SPB * 210 / 4; i += NT)
                ((f4*)gdst)[i] = ((const f4*)uh.sout)[i];
        } else {
            for (int i = tid; i < nval; i += NT) gdst[i] = uh.sout[i];
        }
    }
}

extern "C" void kernel_launch(void* const* d_in, const int* in_sizes, int n_in,
                              void* d_out, int out_size, void* d_ws, size_t ws_size,
                              hipStream_t stream) {
    const float* state     = (const float*)d_in[0];
    const float* pos_intra = (const float*)d_in[1];
    const float* wq_i      = (const float*)d_in[2];
    const float* bq_i      = (const float*)d_in[3];
    const float* wk_i      = (const float*)d_in[4];
    const float* bk_i      = (const float*)d_in[5];
    const float* wv_i      = (const float*)d_in[6];
    const float* bv_i      = (const float*)d_in[7];
    const float* pos_inter = (const float*)d_in[8];
    const float* wq        = (const float*)d_in[9];
    const float* bq        = (const float*)d_in[10];
    const float* wk        = (const float*)d_in[11];
    const float* bk        = (const float*)d_in[12];
    const float* wv        = (const float*)d_in[13];
    const float* bv        = (const float*)d_in[14];
    float* outp = (float*)d_out;

    const int B = in_sizes[0] / 100;
    const int grid = (B + SPB - 1) / SPB;
    hipLaunchKernelGGL(crazy_attn_kernel, dim3(grid), dim3(NT), 0, stream,
                       state, pos_intra, wq_i, bq_i, wk_i, bk_i, wv_i, bv_i,
                       pos_inter, wq, bq, wk, bk, wv, bv, outp, B);
}

// Round 11
// 22.190 us; speedup vs baseline: 1.5159x; 1.0166x over previous
//
#include <hip/hip_runtime.h>

typedef __fp16 h2 __attribute__((ext_vector_type(2)));
typedef __fp16 h4 __attribute__((ext_vector_type(4)));
typedef __fp16 h8 __attribute__((ext_vector_type(8)));
typedef float  f4 __attribute__((ext_vector_type(4)));
typedef float  f2 __attribute__((ext_vector_type(2)));

#if __has_builtin(__builtin_amdgcn_fdot2)
#define FDOT2(a, b, c) __builtin_amdgcn_fdot2((a), (b), (c), false)
#else
#define FDOT2(a, b, c) ((c) + (float)(a)[0] * (float)(b)[0] + (float)(a)[1] * (float)(b)[1])
#endif

#define SPB 16
#define NT  320   // 20 threads/sample: (row 0..9) x (e 0..1); 5 waves/block

// lane^1 exchange on the VALU pipe (quad_perm [1,0,3,2]), no LDS traffic
__device__ __forceinline__ float dpp_xor1(float x) {
    int i = __builtin_amdgcn_mov_dpp(__float_as_int(x), 0xB1, 0xF, 0xF, true);
    return __int_as_float(i);
}

// LDS:
//  X  [160][32] fp16 : x rows, K-padded: [20 data][1.0 bias][11 zeros]
//  WT [96][32]  fp16 : W^T rows, 32-row sections (q 0..31, k 32..63, v 64..95),
//                      valid cols 0..20 of each section, rest zero (MFMA-tile aligned)
//  QKV[160][72] fp16 : per x-row [q 0..23][k 24..47][v 48..71] (pads exact zero)
struct SMa {
    __fp16 X [160 * 32];    // 10240 B
    __fp16 WT[96 * 32];     //  6144 B
};
union UHead { SMa a; float sout[SPB * 210]; };   // 13440 B <= 16384 B alias

__global__ __launch_bounds__(NT, 5)
void crazy_attn_kernel(const float* __restrict__ state,      // (B,100)
                       const float* __restrict__ pos_intra,  // (10,1)
                       const float* __restrict__ wq_i, const float* __restrict__ bq_i,
                       const float* __restrict__ wk_i, const float* __restrict__ bk_i,
                       const float* __restrict__ wv_i, const float* __restrict__ bv_i,
                       const float* __restrict__ pos_inter,  // (10,20)
                       const float* __restrict__ wq, const float* __restrict__ bq,
                       const float* __restrict__ wk, const float* __restrict__ bk,
                       const float* __restrict__ wv, const float* __restrict__ bv,
                       float* __restrict__ out, int B)
{
    __shared__ UHead uh;
    __shared__ __fp16 QKV[160 * 72];   // 23040 B (total 39424 B -> 4 blocks/CU)

    const int tid  = threadIdx.x;
    const int e    = tid & 1;               // pair lane (xor-1 partner)
    const int rr   = (tid >> 1) % 10;       // frame == inter row
    const int samp = tid / 20;              // 0..15
    const int gs   = blockIdx.x * SPB + samp;
    const int gsc  = (gs < B) ? gs : (B - 1);

    // ---- stage 0: W^T -> LDS (fp16, 32-row sections, bias at k=20) ----
    if (tid < 96) {
        const int sec = tid >> 5, within = tid & 31;   // sec 0=q 1=k 2=v
        const bool valid = within < 21;
        const float* W  = (sec == 1) ? wk : (sec == 2) ? wv : wq;
        const float* Bb = (sec == 1) ? bk : (sec == 2) ? bv : bq;
        union { uint4 u4[4]; h2 hh[16]; } T;
        #pragma unroll
        for (int p = 0; p < 16; ++p) {
            const int j0 = 2 * p, j1 = 2 * p + 1;
            float lo = 0.f, hi = 0.f;
            if (valid) {
                lo = (j0 < 20) ? W[j0 * 21 + within] : ((j0 == 20) ? Bb[within] : 0.f);
                hi = (j1 < 20) ? W[j1 * 21 + within] : 0.f;
            }
            T.hh[p] = __builtin_amdgcn_cvt_pkrtz(lo, hi);
        }
        uint4* wd = (uint4*)&uh.a.WT[tid * 32];
        wd[0] = T.u4[0]; wd[1] = T.u4[1]; wd[2] = T.u4[2]; wd[3] = T.u4[3];
    }
    __syncthreads();   // B0: WT staged (cheap, before the exp-heavy phase)

    // ---- stage A: intra attention; e splits query rows (s = 2*si + e) ----
    {
        const float* sp = state + (size_t)gsc * 100 + rr * 10;
        float xv[10];
        #pragma unroll
        for (int t2 = 0; t2 < 5; ++t2) {               // float2 loads (8B, aligned)
            const f2 v = *(const f2*)&sp[t2 * 2];
            xv[2 * t2]     = v[0] + pos_intra[2 * t2];
            xv[2 * t2 + 1] = v[1] + pos_intra[2 * t2 + 1];
        }
        float xmx = xv[0], xmn = xv[0];
        #pragma unroll
        for (int t = 1; t < 10; ++t) { xmx = fmaxf(xmx, xv[t]); xmn = fminf(xmn, xv[t]); }

        float res[2][5];   // [h][si]
        #pragma unroll
        for (int h = 0; h < 2; ++h) {
            const float wqh = wq_i[h], bqh = bq_i[h];
            const float wkh = wk_i[h];
            const float wvh = wv_i[h], bvh = bv_i[h];
            float vh[10];
            #pragma unroll
            for (int t = 0; t < 10; ++t) vh[t] = fmaf(xv[t], wvh, bvh);
            #pragma unroll
            for (int si = 0; si < 5; ++si) {
                const float c0 = fmaf(xv[2 * si],     wqh, bqh) * wkh;
                const float c1 = fmaf(xv[2 * si + 1], wqh, bqh) * wkh;
                const float c  = e ? c1 : c0;                      // s = 2*si+e
                const float mx = c * ((c >= 0.f) ? xmx : xmn);     // exact max
                const float cL = c * 1.44269504f;
                const float mL = mx * 1.44269504f;
                float sum = 0.f, o = 0.f;
                #pragma unroll
                for (int t = 0; t < 10; ++t) {
                    const float ex = __builtin_amdgcn_exp2f(fmaf(cL, xv[t], -mL));
                    sum += ex; o = fmaf(ex, vh[t], o);
                }
                res[h][si] = o * __builtin_amdgcn_rcpf(sum);
            }
        }
        // write 5 feature-pairs (k = 2s, 2s+1), s = 2*si+e
        __fp16* xrow = &uh.a.X[(samp * 10 + rr) * 32];
        const float* prow = pos_inter + rr * 20;
        #pragma unroll
        for (int si = 0; si < 5; ++si) {
            const int s = 2 * si + e;
            *(h2*)&xrow[2 * s] = __builtin_amdgcn_cvt_pkrtz(res[0][si] + prow[2 * s],
                                                            res[1][si] + prow[2 * s + 1]);
        }
        // pads: e0 -> pairs k=20(bias),22,24 ; e1 -> 26,28,30
        const h2 z  = __builtin_amdgcn_cvt_pkrtz(0.f, 0.f);
        const h2 bz = __builtin_amdgcn_cvt_pkrtz(1.0f, 0.f);
        #pragma unroll
        for (int j = 0; j < 3; ++j) {
            const int k = 20 + 2 * (3 * e + j);
            *(h2*)&xrow[k] = (e == 0 && j == 0) ? bz : z;
        }
    }

    // ---- stage B (fused, NO barrier): wave w's stage-A rows 32w..32w+31 are
    // exactly proj tiles nt=2w,2w+1; same-wave LDS RAW is lgkmcnt-ordered.
    // D(96x160) = WT(96x32) . X^T(32x160), 12 MFMA/wave
    {
        const int l  = tid & 63;
        const int w  = tid >> 6;        // wave 0..4
        const int lr = l & 15, lh = l >> 4;
        h8 afrag[6];
        #pragma unroll
        for (int mt = 0; mt < 6; ++mt)
            afrag[mt] = *(const h8*)&uh.a.WT[(mt * 16 + lr) * 32 + lh * 8];
        #pragma unroll
        for (int i = 0; i < 2; ++i) {
            const int xrow = (2 * w + i) * 16 + lr;    // own-wave rows only
            const h8 bfrag = *(const h8*)&uh.a.X[xrow * 32 + lh * 8];
            #pragma unroll
            for (int mt = 0; mt < 6; ++mt) {
                f4 acc = {0.f, 0.f, 0.f, 0.f};
                acc = __builtin_amdgcn_mfma_f32_16x16x32_f16(afrag[mt], bfrag, acc, 0, 0, 0);
                const int m0     = mt * 16 + lh * 4;   // 4 consecutive m per lane
                const int sec    = m0 >> 5;            // 0=q 1=k 2=v
                const int within = m0 & 31;
                if (within <= 20) {                    // cols 21..23 are exact zeros
                    union { h2 p2[2]; h4 p4; } P;
                    P.p2[0] = __builtin_amdgcn_cvt_pkrtz(acc[0], acc[1]);
                    P.p2[1] = __builtin_amdgcn_cvt_pkrtz(acc[2], acc[3]);
                    *(h4*)&QKV[xrow * 72 + sec * 24 + within] = P.p4;
                }
            }
        }
    }
    __syncthreads();   // B2: QKV staged; X/WT dead -> sout alias safe

    // ---- stage C: inter attention; e splits K/V tiles (t = 2i+e) ----
    {
        const __fp16* samprows = &QKV[samp * 10 * 72];
        union { uint4 u4[3]; h2 hh[12]; } Q;
        {
            const uint4* qsrc = (const uint4*)&samprows[rr * 72];   // cols 0..23
            Q.u4[0] = qsrc[0]; Q.u4[1] = qsrc[1]; Q.u4[2] = qsrc[2];
        }
        float mysc[5];
        #pragma unroll
        for (int i = 0; i < 5; ++i) {
            const int t = 2 * i + e;
            union { uint4 u4[3]; h2 hh[12]; } K;
            const uint4* ks = (const uint4*)&samprows[t * 72 + 24]; // cols 24..47
            K.u4[0] = ks[0]; K.u4[1] = ks[1]; K.u4[2] = ks[2];
            float d = 0.f;
            #pragma unroll
            for (int p = 0; p < 11; ++p) d = FDOT2(Q.hh[p], K.hh[p], d);
            mysc[i] = d * 0.21821789023599239f;   // 1/sqrt(21)
        }
        // cross-e softmax: max and sum via DPP xor-1 (no LDS)
        float mymax = mysc[0];
        #pragma unroll
        for (int i = 1; i < 5; ++i) mymax = fmaxf(mymax, mysc[i]);
        const float m = fmaxf(mymax, dpp_xor1(mymax));
        float pe[5], psum = 0.f;
        #pragma unroll
        for (int i = 0; i < 5; ++i) {
            pe[i] = __builtin_amdgcn_exp2f((mysc[i] - m) * 1.44269504f);
            psum += pe[i];
        }
        const float sum = psum + dpp_xor1(psum);
        const float inv = __builtin_amdgcn_rcpf(sum);

        float acc[21];
        #pragma unroll
        for (int c = 0; c < 21; ++c) acc[c] = 0.f;
        #pragma unroll
        for (int i = 0; i < 5; ++i) {
            const int t = 2 * i + e;
            union { uint4 u4[3]; h2 hh[12]; } V;
            const uint4* vs = (const uint4*)&samprows[t * 72 + 48]; // cols 48..71
            V.u4[0] = vs[0]; V.u4[1] = vs[1]; V.u4[2] = vs[2];
            const float a = pe[i] * inv;
            #pragma unroll
            for (int c = 0; c < 21; ++c)
                acc[c] = fmaf(a, (float)V.hh[c >> 1][c & 1], acc[c]);  // v_fma_mix
        }
        // cross-e reduce via DPP; e0 lane writes the row
        #pragma unroll
        for (int c = 0; c < 21; ++c) acc[c] += dpp_xor1(acc[c]);
        if (e == 0) {
            float* dst = &uh.sout[(samp * 10 + rr) * 21];
            #pragma unroll
            for (int c = 0; c < 21; ++c) dst[c] = acc[c];
        }
    }
    __syncthreads();   // B3: sout staged

    // ---- epilogue: coalesced block copy ----
    {
        const int samp0 = blockIdx.x * SPB;
        const int nrem  = B - samp0;
        const int nval  = ((nrem < SPB) ? nrem : SPB) * 210;
        float* gdst = out + (size_t)samp0 * 210;
        if (nval == SPB * 210) {
            for (int i = tid; i < SPB * 210 / 4; i += NT)
                ((f4*)gdst)[i] = ((const f4*)uh.sout)[i];
        } else {
            for (int i = tid; i < nval; i += NT) gdst[i] = uh.sout[i];
        }
    }
}

extern "C" void kernel_launch(void* const* d_in, const int* in_sizes, int n_in,
                              void* d_out, int out_size, void* d_ws, size_t ws_size,
                              hipStream_t stream) {
    const float* state     = (const float*)d_in[0];
    const float* pos_intra = (const float*)d_in[1];
    const float* wq_i      = (const float*)d_in[2];
    const float* bq_i      = (const float*)d_in[3];
    const float* wk_i      = (const float*)d_in[4];
    const float* bk_i      = (const float*)d_in[5];
    const float* wv_i      = (const float*)d_in[6];
    const float* bv_i      = (const float*)d_in[7];
    const float* pos_inter = (const float*)d_in[8];
    const float* wq        = (const float*)d_in[9];
    const float* bq        = (const float*)d_in[10];
    const float* wk        = (const float*)d_in[11];
    const float* bk        = (const float*)d_in[12];
    const float* wv        = (const float*)d_in[13];
    const float* bv        = (const float*)d_in[14];
    float* outp = (float*)d_out;

    const int B = in_sizes[0] / 100;
    const int grid = (B + SPB - 1) / SPB;
    hipLaunchKernelGGL(crazy_attn_kernel, dim3(grid), dim3(NT), 0, stream,
                       state, pos_intra, wq_i, bq_i, wk_i, bk_i, wv_i, bv_i,
                       pos_inter, wq, bq, wk, bk, wv, bv, outp, B);
}